// Round 1
// baseline (1337.872 us; speedup 1.0000x reference)
//
#include <hip/hip_runtime.h>
#include <math.h>

// Problem constants (match reference setup_inputs)
constexpr int G_N  = 10000;   // inner graphs / outer nodes
constexpr int NI_N = 32;      // nodes per inner graph
constexpr int EI_N = 128;     // edges per inner graph
constexpr int EO_N = 160000;  // outer edges
constexpr int FIN  = 64;      // inner input feature dim
constexpr int HD   = 128;     // hidden dim (= F_G)
constexpr int NCLS = 32;      // output classes

// ---------------------------------------------------------------------------
// Inner-graph GCN: one block (256 threads) per graph.
// Densify D^-1/2 A D^-1/2 into M[32][32] (built once; same for all 3 layers),
// then each layer is:  T = M @ h   (stored transposed [K][32] in LDS)
//                      h = relu?(T @ W + b)
// ---------------------------------------------------------------------------

// agg step: sT[j][n] = sum_k M[n][k] * sIn[k][j]   (sIn row stride = HD)
template <int K>
__device__ __forceinline__ void agg_step(const float* __restrict__ sM,
                                         const float* __restrict__ sIn,
                                         float* __restrict__ sT, int t) {
  constexpr int NC4 = K / 4;        // 4-wide column groups
  constexpr int TILES = 8 * NC4;    // 8 row groups of 4 nodes
  if (t < TILES) {
    const int r = t / NC4;          // node group (0..7)
    const int c = t % NC4;          // feature-col group
    float acc[4][4] = {};
#pragma unroll 8
    for (int k = 0; k < NI_N; ++k) {
      const float4 hv = *(const float4*)&sIn[k * HD + c * 4];
#pragma unroll
      for (int i = 0; i < 4; ++i) {
        const float m = sM[(r * 4 + i) * 33 + k];
        acc[i][0] = fmaf(m, hv.x, acc[i][0]);
        acc[i][1] = fmaf(m, hv.y, acc[i][1]);
        acc[i][2] = fmaf(m, hv.z, acc[i][2]);
        acc[i][3] = fmaf(m, hv.w, acc[i][3]);
      }
    }
    // transposed store: sT[(col)*32 + node]
#pragma unroll
    for (int j = 0; j < 4; ++j) {
      float4 v = make_float4(acc[0][j], acc[1][j], acc[2][j], acc[3][j]);
      *(float4*)&sT[(c * 4 + j) * 32 + r * 4] = v;
    }
  }
}

// mm step: sOut[n][j] = relu?( sum_k sT[k][n] * W[k][j] + b[j] )
template <int Kin, bool RELU>
__device__ __forceinline__ void mm_step(const float* __restrict__ sT,
                                        const float* __restrict__ W,
                                        const float* __restrict__ bias,
                                        float* __restrict__ sOut, int t) {
  const int r = t >> 5;   // node group 0..7
  const int c = t & 31;   // output-col group 0..31
  float acc[4][4] = {};
#pragma unroll 8
  for (int k = 0; k < Kin; ++k) {
    const float4 av = *(const float4*)&sT[k * 32 + r * 4];     // broadcast read
    const float4 wv = *(const float4*)&W[k * HD + c * 4];      // L2-resident
    acc[0][0] = fmaf(av.x, wv.x, acc[0][0]);
    acc[0][1] = fmaf(av.x, wv.y, acc[0][1]);
    acc[0][2] = fmaf(av.x, wv.z, acc[0][2]);
    acc[0][3] = fmaf(av.x, wv.w, acc[0][3]);
    acc[1][0] = fmaf(av.y, wv.x, acc[1][0]);
    acc[1][1] = fmaf(av.y, wv.y, acc[1][1]);
    acc[1][2] = fmaf(av.y, wv.z, acc[1][2]);
    acc[1][3] = fmaf(av.y, wv.w, acc[1][3]);
    acc[2][0] = fmaf(av.z, wv.x, acc[2][0]);
    acc[2][1] = fmaf(av.z, wv.y, acc[2][1]);
    acc[2][2] = fmaf(av.z, wv.z, acc[2][2]);
    acc[2][3] = fmaf(av.z, wv.w, acc[2][3]);
    acc[3][0] = fmaf(av.w, wv.x, acc[3][0]);
    acc[3][1] = fmaf(av.w, wv.y, acc[3][1]);
    acc[3][2] = fmaf(av.w, wv.z, acc[3][2]);
    acc[3][3] = fmaf(av.w, wv.w, acc[3][3]);
  }
  const float4 bv = *(const float4*)&bias[c * 4];
#pragma unroll
  for (int i = 0; i < 4; ++i) {
    float4 v = make_float4(acc[i][0] + bv.x, acc[i][1] + bv.y,
                           acc[i][2] + bv.z, acc[i][3] + bv.w);
    if (RELU) {
      v.x = fmaxf(v.x, 0.f); v.y = fmaxf(v.y, 0.f);
      v.z = fmaxf(v.z, 0.f); v.w = fmaxf(v.w, 0.f);
    }
    *(float4*)&sOut[(r * 4 + i) * HD + c * 4] = v;
  }
}

__global__ __launch_bounds__(256) void inner_gcn_kernel(
    const float* __restrict__ feats, const int* __restrict__ src,
    const int* __restrict__ dst,
    const float* __restrict__ Wi0, const float* __restrict__ bi0,
    const float* __restrict__ Wi1, const float* __restrict__ bi1,
    const float* __restrict__ Wi2, const float* __restrict__ bi2,
    float* __restrict__ feat_out) {
  __shared__ __align__(16) float sM[NI_N * 33];    // padded adjacency (norm'd)
  __shared__ __align__(16) float sH[NI_N * HD];    // node features, row-major
  __shared__ __align__(16) float sT[HD * NI_N];    // agg, transposed [col][node]
  __shared__ float sNorm[NI_N];

  const int t = threadIdx.x;
  const int g = blockIdx.x;

  // build M = D^-1/2 A D^-1/2 (deg from dst, matching reference)
  for (int i = t; i < NI_N * 33; i += 256) sM[i] = 0.f;
  __syncthreads();
  if (t < EI_N) {
    const int s = src[g * EI_N + t];
    const int d = dst[g * EI_N + t];
    atomicAdd(&sM[d * 33 + s], 1.0f);
  }
  __syncthreads();
  if (t < NI_N) {
    float deg = 0.f;
    for (int m = 0; m < NI_N; ++m) deg += sM[t * 33 + m];
    sNorm[t] = (deg > 0.f) ? (1.0f / sqrtf(deg)) : 1.0f;
  }
  __syncthreads();
  for (int i = t; i < NI_N * NI_N; i += 256) {
    const int n = i >> 5, m = i & 31;
    sM[n * 33 + m] *= sNorm[n] * sNorm[m];
  }
  // load h0 (32 x 64) into sH with row stride HD
  {
    const float4* src4 = (const float4*)(feats + (size_t)g * NI_N * FIN);
    for (int i = t; i < NI_N * FIN / 4; i += 256) {
      const int n = i / (FIN / 4), q = i % (FIN / 4);
      *(float4*)&sH[n * HD + q * 4] = src4[i];
    }
  }
  __syncthreads();

  // layer 0: 64 -> 128, relu
  agg_step<FIN>(sM, sH, sT, t);
  __syncthreads();
  mm_step<FIN, true>(sT, Wi0, bi0, sH, t);
  __syncthreads();
  // layer 1: 128 -> 128, relu
  agg_step<HD>(sM, sH, sT, t);
  __syncthreads();
  mm_step<HD, true>(sT, Wi1, bi1, sH, t);
  __syncthreads();
  // layer 2: 128 -> 128, no relu
  agg_step<HD>(sM, sH, sT, t);
  __syncthreads();
  mm_step<HD, false>(sT, Wi2, bi2, sH, t);
  __syncthreads();

  // mean over nodes -> feat_out[g][0..127]
  if (t < HD) {
    float s = 0.f;
    for (int n = 0; n < NI_N; ++n) s += sH[n * HD + t];
    feat_out[(size_t)g * HD + t] = s * (1.0f / NI_N);
  }
}

// ---------------------------------------------------------------------------
// Outer GCN over G=10000 nodes, 160K edges
// ---------------------------------------------------------------------------
__global__ __launch_bounds__(256) void outer_deg_kernel(
    const int* __restrict__ dst, float* __restrict__ deg) {
  const int e = blockIdx.x * 256 + threadIdx.x;
  if (e < EO_N) atomicAdd(&deg[dst[e]], 1.0f);
}

__global__ __launch_bounds__(256) void outer_norm_kernel(float* __restrict__ deg) {
  const int n = blockIdx.x * 256 + threadIdx.x;
  if (n < G_N) {
    const float d = deg[n];
    deg[n] = (d > 0.f) ? (1.0f / sqrtf(d)) : 1.0f;
  }
}

// scatter: agg[dst] += h[src] * norm[src]; one thread per (edge, 4-feat group)
template <int F>
__global__ __launch_bounds__(256) void scatter_kernel(
    const float* __restrict__ h, const int* __restrict__ src,
    const int* __restrict__ dst, const float* __restrict__ norm,
    float* __restrict__ agg) {
  constexpr int Q = F / 4;
  const long long gid = (long long)blockIdx.x * 256 + threadIdx.x;
  const int e = (int)(gid / Q);
  const int q = (int)(gid % Q);
  if (e >= EO_N) return;
  const int s = src[e], d = dst[e];
  const float ns = norm[s];
  const float4 v = *(const float4*)&h[(size_t)s * F + q * 4];
  float* p = &agg[(size_t)d * F + q * 4];
  atomicAdd(p + 0, v.x * ns);
  atomicAdd(p + 1, v.y * ns);
  atomicAdd(p + 2, v.z * ns);
  atomicAdd(p + 3, v.w * ns);
}

// out[n] = relu?( (agg[n]*norm[n]) @ W + b ); 32 rows per block
template <int Kin, int Nout, bool RELU>
__global__ __launch_bounds__(256) void rowmm_kernel(
    const float* __restrict__ in, const float* __restrict__ norm,
    const float* __restrict__ W, const float* __restrict__ bias,
    float* __restrict__ out) {
  __shared__ __align__(16) float sIn[32 * Kin];
  const int t = threadIdx.x;
  const int row0 = blockIdx.x * 32;
  constexpr int QK = Kin / 4;
  for (int i = t; i < 32 * QK; i += 256) {
    const int rr = i / QK, q = i % QK;
    const int row = row0 + rr;
    float4 v = make_float4(0.f, 0.f, 0.f, 0.f);
    if (row < G_N) {
      v = *(const float4*)&in[(size_t)row * Kin + q * 4];
      const float nn = norm[row];
      v.x *= nn; v.y *= nn; v.z *= nn; v.w *= nn;
    }
    *(float4*)&sIn[rr * Kin + q * 4] = v;
  }
  __syncthreads();
  constexpr int NC4 = Nout / 4;
  constexpr int TILES = 8 * NC4;
  if (t < TILES) {
    const int r = t / NC4, c = t % NC4;
    float acc[4][4] = {};
#pragma unroll 8
    for (int k = 0; k < Kin; ++k) {
      const float4 wv = *(const float4*)&W[k * Nout + c * 4];
      const float a0 = sIn[(r * 4 + 0) * Kin + k];
      const float a1 = sIn[(r * 4 + 1) * Kin + k];
      const float a2 = sIn[(r * 4 + 2) * Kin + k];
      const float a3 = sIn[(r * 4 + 3) * Kin + k];
      acc[0][0] = fmaf(a0, wv.x, acc[0][0]);
      acc[0][1] = fmaf(a0, wv.y, acc[0][1]);
      acc[0][2] = fmaf(a0, wv.z, acc[0][2]);
      acc[0][3] = fmaf(a0, wv.w, acc[0][3]);
      acc[1][0] = fmaf(a1, wv.x, acc[1][0]);
      acc[1][1] = fmaf(a1, wv.y, acc[1][1]);
      acc[1][2] = fmaf(a1, wv.z, acc[1][2]);
      acc[1][3] = fmaf(a1, wv.w, acc[1][3]);
      acc[2][0] = fmaf(a2, wv.x, acc[2][0]);
      acc[2][1] = fmaf(a2, wv.y, acc[2][1]);
      acc[2][2] = fmaf(a2, wv.z, acc[2][2]);
      acc[2][3] = fmaf(a2, wv.w, acc[2][3]);
      acc[3][0] = fmaf(a3, wv.x, acc[3][0]);
      acc[3][1] = fmaf(a3, wv.y, acc[3][1]);
      acc[3][2] = fmaf(a3, wv.z, acc[3][2]);
      acc[3][3] = fmaf(a3, wv.w, acc[3][3]);
    }
    const float4 bv = *(const float4*)&bias[c * 4];
#pragma unroll
    for (int i = 0; i < 4; ++i) {
      const int row = row0 + r * 4 + i;
      if (row < G_N) {
        float4 v = make_float4(acc[i][0] + bv.x, acc[i][1] + bv.y,
                               acc[i][2] + bv.z, acc[i][3] + bv.w);
        if (RELU) {
          v.x = fmaxf(v.x, 0.f); v.y = fmaxf(v.y, 0.f);
          v.z = fmaxf(v.z, 0.f); v.w = fmaxf(v.w, 0.f);
        }
        *(float4*)&out[(size_t)row * Nout + c * 4] = v;
      }
    }
  }
}

// ---------------------------------------------------------------------------
extern "C" void kernel_launch(void* const* d_in, const int* in_sizes, int n_in,
                              void* d_out, int out_size, void* d_ws,
                              size_t ws_size, hipStream_t stream) {
  const float* feats = (const float*)d_in[0];
  const int* isrc = (const int*)d_in[1];
  const int* idst = (const int*)d_in[2];
  const int* osrc = (const int*)d_in[3];
  const int* odst = (const int*)d_in[4];
  const float* Wi0 = (const float*)d_in[5];
  const float* bi0 = (const float*)d_in[6];
  const float* Wi1 = (const float*)d_in[7];
  const float* bi1 = (const float*)d_in[8];
  const float* Wi2 = (const float*)d_in[9];
  const float* bi2 = (const float*)d_in[10];
  const float* Wo0 = (const float*)d_in[11];
  const float* bo0 = (const float*)d_in[12];
  const float* Wo1 = (const float*)d_in[13];
  const float* bo1 = (const float*)d_in[14];
  const float* Wo2 = (const float*)d_in[15];
  const float* bo2 = (const float*)d_in[16];
  float* out = (float*)d_out;

  float* ws = (float*)d_ws;
  float* feat = ws;                       // [G,128]  (also reused as h1)
  float* h0   = ws + (size_t)G_N * HD;    // [G,128]
  float* agg  = ws + (size_t)2 * G_N * HD;// [G,128]
  float* nrm  = ws + (size_t)3 * G_N * HD;// [G]

  // inner GCNs -> pooled graph features
  inner_gcn_kernel<<<G_N, 256, 0, stream>>>(feats, isrc, idst, Wi0, bi0, Wi1,
                                            bi1, Wi2, bi2, feat);

  // outer degree / norm
  hipMemsetAsync(nrm, 0, G_N * sizeof(float), stream);
  outer_deg_kernel<<<(EO_N + 255) / 256, 256, 0, stream>>>(odst, nrm);
  outer_norm_kernel<<<(G_N + 255) / 256, 256, 0, stream>>>(nrm);

  const int sc_grid = (EO_N * (HD / 4) + 255) / 256;
  const int mm_grid = (G_N + 31) / 32;

  // outer layer 0: feat -> h0 (relu)
  hipMemsetAsync(agg, 0, (size_t)G_N * HD * sizeof(float), stream);
  scatter_kernel<HD><<<sc_grid, 256, 0, stream>>>(feat, osrc, odst, nrm, agg);
  rowmm_kernel<HD, HD, true><<<mm_grid, 256, 0, stream>>>(agg, nrm, Wo0, bo0, h0);

  // outer layer 1: h0 -> feat (relu; feat buffer reused)
  hipMemsetAsync(agg, 0, (size_t)G_N * HD * sizeof(float), stream);
  scatter_kernel<HD><<<sc_grid, 256, 0, stream>>>(h0, osrc, odst, nrm, agg);
  rowmm_kernel<HD, HD, true><<<mm_grid, 256, 0, stream>>>(agg, nrm, Wo1, bo1, feat);

  // outer layer 2: feat -> out (no relu, Nout=32)
  hipMemsetAsync(agg, 0, (size_t)G_N * HD * sizeof(float), stream);
  scatter_kernel<HD><<<sc_grid, 256, 0, stream>>>(feat, osrc, odst, nrm, agg);
  rowmm_kernel<HD, NCLS, false><<<mm_grid, 256, 0, stream>>>(agg, nrm, Wo2, bo2, out);
}

// Round 7
// 258.605 us; speedup vs baseline: 5.1734x; 5.1734x over previous
//
#include <hip/hip_runtime.h>
#include <math.h>

// Round-6 resubmission of the Round-1 MFMA+CSR kernel (rounds 2-6 hit the
// same dead container; source unchanged so the A/B vs round 1 stays clean).

// Problem constants (match reference setup_inputs)
constexpr int G_N  = 10000;   // inner graphs / outer nodes
constexpr int NI_N = 32;      // nodes per inner graph
constexpr int EI_N = 128;     // edges per inner graph
constexpr int EO_N = 160000;  // outer edges
constexpr int FIN  = 64;      // inner input feature dim
constexpr int HD   = 128;     // hidden dim (= F_G)
constexpr int NCLS = 32;      // output classes

typedef short bf16x8 __attribute__((ext_vector_type(8)));   // 8 bf16 (4 VGPRs)
typedef float f32x4  __attribute__((ext_vector_type(4)));   // MFMA accumulator

#define MFMA16(a, b, c) __builtin_amdgcn_mfma_f32_16x16x32_bf16((a), (b), (c), 0, 0, 0)

// fp32 -> bf16, round-to-nearest-even (no NaN handling needed for this data)
__device__ __forceinline__ unsigned short f2bf(float x) {
  unsigned int u = __builtin_bit_cast(unsigned int, x);
  u += 0x7fffu + ((u >> 16) & 1u);
  return (unsigned short)(u >> 16);
}

// ---------------------------------------------------------------------------
// Weight pre-pack: W[K][128] fp32 -> B-fragment order bf16.
// Wpack[(ct*KB + kb)*64 + lane][j] = W[32*kb + 8*(lane>>4) + j][16*ct + (lane&15)]
// ---------------------------------------------------------------------------
__global__ __launch_bounds__(256) void pack_w_kernel(const float* __restrict__ W,
                                                     int K, short* __restrict__ out) {
  const int idx = blockIdx.x * 256 + threadIdx.x;   // one thread per (ct,kb,lane)
  const int KB = K >> 5;
  const int total = 8 * KB * 64;
  if (idx >= total) return;
  const int lane = idx & 63;
  const int ctkb = idx >> 6;            // = ct*KB + kb
  const int kb = ctkb % KB;
  const int ct = ctkb / KB;
  const int col = 16 * ct + (lane & 15);
  const int k0 = 32 * kb + 8 * (lane >> 4);
#pragma unroll
  for (int j = 0; j < 8; ++j)
    out[idx * 8 + j] = (short)f2bf(W[(k0 + j) * HD + col]);
}

// ---------------------------------------------------------------------------
// One GCN layer entirely in MFMA:
//   step 1: T = M @ h           (K = 32 nodes, one MFMA per 16x16 tile)
//   step 2: H = T @ W + b [relu] (K = 32*KB feats)
// Fragment-packed LDS layouts so every MFMA operand load is a dense b128 read.
// ---------------------------------------------------------------------------
template <int NCT_IN, bool RELU, bool LAST>
__device__ __forceinline__ void gcn_layer(
    int w, int l, const short* __restrict__ sApackM, short* __restrict__ sHpack,
    short* __restrict__ sTpack, const short* __restrict__ Wpack,
    const float* __restrict__ bias, float* __restrict__ sPool) {
  constexpr int KB = NCT_IN / 2;        // K blocks of 32 for step 2
  const int rt = w >> 1;                // node row-block (0..1) this wave owns
  const int g = l >> 4, c15 = l & 15;
  const f32x4 z = {0.f, 0.f, 0.f, 0.f};

  // ---- step 1: T = M @ h ----
  const bf16x8 am = *(const bf16x8*)&sApackM[(rt * 64 + l) * 8];
#pragma unroll
  for (int i = 0; i < NCT_IN / 2; ++i) {
    const int ct = (w & 1) * (NCT_IN / 2) + i;     // feat tile of h
    const bf16x8 bh = *(const bf16x8*)&sHpack[(ct * 64 + l) * 8];
    f32x4 d = MFMA16(am, bh, z);
    // D(col=16ct+c15 [feat], row=16rt+4g+r [node]) -> A-frag pack of T
    const int kb = ct >> 1;
    const int hi = ((ct & 1) << 1) | (c15 >> 3);
    const int jj = l & 7;
#pragma unroll
    for (int r = 0; r < 4; ++r) {
      const int lanep = 4 * g + r + 16 * hi;
      sTpack[((rt * 4 + kb) * 64 + lanep) * 8 + jj] = (short)f2bf(d[r]);
    }
  }
  __syncthreads();

  // ---- step 2: H = T @ W (+bias, relu / pool) ----
  bf16x8 a[KB];
#pragma unroll
  for (int kb = 0; kb < KB; ++kb)
    a[kb] = *(const bf16x8*)&sTpack[((rt * 4 + kb) * 64 + l) * 8];
#pragma unroll
  for (int i = 0; i < 4; ++i) {
    const int ct2 = (w & 1) * 4 + i;               // output feat tile
    f32x4 acc = z;
#pragma unroll
    for (int kb = 0; kb < KB; ++kb) {
      const bf16x8 bw = *(const bf16x8*)&Wpack[((ct2 * KB + kb) * 64 + l) * 8];
      acc = MFMA16(a[kb], bw, acc);
    }
    const int f = 16 * ct2 + c15;
    const float bv = bias[f];
    if (LAST) {
      // mean-pool contribution: sum this lane's 4 node-rows
      const float s = (acc[0] + bv) + (acc[1] + bv) + (acc[2] + bv) + (acc[3] + bv);
      atomicAdd(&sPool[f], s);
    } else {
      unsigned short u[4];
#pragma unroll
      for (int r = 0; r < 4; ++r) {
        float v = acc[r] + bv;
        if (RELU) v = fmaxf(v, 0.f);
        u[r] = f2bf(v);
      }
      // D(col=f, rows n=16rt+4g+r) -> B-frag pack of next h: contiguous j' => b64
      const int g2 = 2 * rt + (g >> 1);
      const int lanep = c15 + 16 * g2;
      const ushort4 pk = make_ushort4(u[0], u[1], u[2], u[3]);
      *(ushort4*)&sHpack[(ct2 * 64 + lanep) * 8 + 4 * (g & 1)] = pk;
    }
  }
  __syncthreads();
}

__global__ __launch_bounds__(256) void inner_gcn_kernel(
    const float* __restrict__ feats, const int* __restrict__ src,
    const int* __restrict__ dst,
    const short* __restrict__ wp0, const float* __restrict__ bi0,
    const short* __restrict__ wp1, const float* __restrict__ bi1,
    const short* __restrict__ wp2, const float* __restrict__ bi2,
    float* __restrict__ feat_out) {
  __shared__ float sM[NI_N * 33];                   // normalized dense adjacency
  __shared__ float sNorm[NI_N];
  __shared__ __align__(16) short sApackM[2 * 64 * 8];   // A-frag of M
  __shared__ __align__(16) short sHpack[8 * 64 * 8];    // B-frag of h
  __shared__ __align__(16) short sTpack[2 * 4 * 64 * 8];// A-frag of T
  __shared__ float sPool[HD];

  const int t = threadIdx.x;
  const int g = blockIdx.x;
  const int w = t >> 6, l = t & 63;

  // ---- build M = D^-1/2 A D^-1/2 ----
  for (int i = t; i < NI_N * 33; i += 256) sM[i] = 0.f;
  if (t < HD) sPool[t] = 0.f;
  __syncthreads();
  if (t < EI_N) {
    const int s = src[g * EI_N + t];
    const int d = dst[g * EI_N + t];
    atomicAdd(&sM[d * 33 + s], 1.0f);
  }
  __syncthreads();
  if (t < NI_N) {
    float deg = 0.f;
    for (int m = 0; m < NI_N; ++m) deg += sM[t * 33 + m];
    sNorm[t] = (deg > 0.f) ? (1.0f / sqrtf(deg)) : 1.0f;
  }
  __syncthreads();
  for (int i = t; i < NI_N * NI_N; i += 256) {
    const int n = i >> 5, m = i & 31;
    sM[n * 33 + m] *= sNorm[n] * sNorm[m];
  }
  __syncthreads();

  // ---- pack M -> A-frag bf16 (1024 elems, 4 per thread) ----
  {
    const int rb = t >> 7;
    const int lane = (t >> 1) & 63;
    const int j0 = (t & 1) * 4;
    const int row = 16 * rb + (lane & 15);
    const int k0 = 8 * (lane >> 4) + j0;
#pragma unroll
    for (int jj = 0; jj < 4; ++jj)
      sApackM[(rb * 64 + lane) * 8 + j0 + jj] = (short)f2bf(sM[row * 33 + k0 + jj]);
  }

  // ---- load h0 (32x64 fp32, coalesced float4) -> B-frag pack ----
  {
    const float4* f4 = (const float4*)(feats + (size_t)g * (NI_N * FIN));
    for (int idx = t; idx < NI_N * FIN / 4; idx += 256) {
      const int n = idx >> 4;          // node
      const int f0 = (idx & 15) * 4;   // feature base (mult of 4, no tile cross)
      const float4 v = f4[idx];
      const int lanebase = 16 * (n >> 3);
      const int jj = n & 7;
      const int ct = f0 >> 4;
      const int c0 = f0 & 15;
      sHpack[(ct * 64 + c0 + 0 + lanebase) * 8 + jj] = (short)f2bf(v.x);
      sHpack[(ct * 64 + c0 + 1 + lanebase) * 8 + jj] = (short)f2bf(v.y);
      sHpack[(ct * 64 + c0 + 2 + lanebase) * 8 + jj] = (short)f2bf(v.z);
      sHpack[(ct * 64 + c0 + 3 + lanebase) * 8 + jj] = (short)f2bf(v.w);
    }
  }
  __syncthreads();

  // ---- 3 layers ----
  gcn_layer<4, true, false>(w, l, sApackM, sHpack, sTpack, wp0, bi0, sPool);
  gcn_layer<8, true, false>(w, l, sApackM, sHpack, sTpack, wp1, bi1, sPool);
  gcn_layer<8, false, true>(w, l, sApackM, sHpack, sTpack, wp2, bi2, sPool);

  // ---- mean over nodes ----
  if (t < HD) feat_out[(size_t)g * HD + t] = sPool[t] * (1.0f / NI_N);
}

// ---------------------------------------------------------------------------
// Outer GCN: CSR build (no float atomics) + gather aggregation + dense rowmm
// ---------------------------------------------------------------------------
__global__ __launch_bounds__(256) void hist_kernel(const int* __restrict__ dst,
                                                   int* __restrict__ degi) {
  const int e = blockIdx.x * 256 + threadIdx.x;
  if (e < EO_N) atomicAdd(&degi[dst[e]], 1);
}

__global__ __launch_bounds__(256) void norm_kernel(const int* __restrict__ degi,
                                                   float* __restrict__ nrm) {
  const int n = blockIdx.x * 256 + threadIdx.x;
  if (n < G_N) {
    const int d = degi[n];
    nrm[n] = (d > 0) ? (1.0f / sqrtf((float)d)) : 1.0f;
  }
}

__global__ __launch_bounds__(1024) void scan_kernel(const int* __restrict__ degi,
                                                    int* __restrict__ start,
                                                    int* __restrict__ cursor) {
  __shared__ int part[1024];
  const int t = threadIdx.x;
  const int base = t * 10;
  int loc[10];
  int s = 0;
#pragma unroll
  for (int k = 0; k < 10; ++k) {
    const int i = base + k;
    const int d = (i < G_N) ? degi[i] : 0;
    loc[k] = s;
    s += d;
  }
  part[t] = s;
  __syncthreads();
  for (int off = 1; off < 1024; off <<= 1) {
    const int v = (t >= off) ? part[t - off] : 0;
    __syncthreads();
    part[t] += v;
    __syncthreads();
  }
  const int excl = (t == 0) ? 0 : part[t - 1];
#pragma unroll
  for (int k = 0; k < 10; ++k) {
    const int i = base + k;
    if (i < G_N) {
      const int st = excl + loc[k];
      start[i] = st;
      cursor[i] = st;
    }
  }
}

__global__ __launch_bounds__(256) void fill_kernel(const int* __restrict__ src,
                                                   const int* __restrict__ dst,
                                                   int* __restrict__ cursor,
                                                   int* __restrict__ esrc) {
  const int e = blockIdx.x * 256 + threadIdx.x;
  if (e < EO_N) {
    const int pos = atomicAdd(&cursor[dst[e]], 1);
    esrc[pos] = src[e];
  }
}

// agg[node] = sum_{e: dst=node} h[src_e] * nrm[src_e]   (half-wave per node)
__global__ __launch_bounds__(256) void gather_kernel(
    const float* __restrict__ h, const int* __restrict__ esrc,
    const int* __restrict__ start, const int* __restrict__ degi,
    const float* __restrict__ nrm, float* __restrict__ agg) {
  const int node = blockIdx.x * 8 + (threadIdx.x >> 5);
  const int q = threadIdx.x & 31;
  if (node >= G_N) return;
  const int s0 = start[node];
  const int cnt = degi[node];
  float4 acc = make_float4(0.f, 0.f, 0.f, 0.f);
  for (int i = 0; i < cnt; ++i) {
    const int s = esrc[s0 + i];
    const float ns = nrm[s];
    const float4 v = *(const float4*)&h[(size_t)s * HD + q * 4];
    acc.x = fmaf(v.x, ns, acc.x);
    acc.y = fmaf(v.y, ns, acc.y);
    acc.z = fmaf(v.z, ns, acc.z);
    acc.w = fmaf(v.w, ns, acc.w);
  }
  *(float4*)&agg[(size_t)node * HD + q * 4] = acc;
}

// out[n] = relu?( (agg[n]*norm[n]) @ W + b ); 32 rows per block (fp32, small)
template <int Kin, int Nout, bool RELU>
__global__ __launch_bounds__(256) void rowmm_kernel(
    const float* __restrict__ in, const float* __restrict__ norm,
    const float* __restrict__ W, const float* __restrict__ bias,
    float* __restrict__ out) {
  __shared__ __align__(16) float sIn[32 * Kin];
  const int t = threadIdx.x;
  const int row0 = blockIdx.x * 32;
  constexpr int QK = Kin / 4;
  for (int i = t; i < 32 * QK; i += 256) {
    const int rr = i / QK, q = i % QK;
    const int row = row0 + rr;
    float4 v = make_float4(0.f, 0.f, 0.f, 0.f);
    if (row < G_N) {
      v = *(const float4*)&in[(size_t)row * Kin + q * 4];
      const float nn = norm[row];
      v.x *= nn; v.y *= nn; v.z *= nn; v.w *= nn;
    }
    *(float4*)&sIn[rr * Kin + q * 4] = v;
  }
  __syncthreads();
  constexpr int NC4 = Nout / 4;
  constexpr int TILES = 8 * NC4;
  if (t < TILES) {
    const int r = t / NC4, c = t % NC4;
    float acc[4][4] = {};
#pragma unroll 8
    for (int k = 0; k < Kin; ++k) {
      const float4 wv = *(const float4*)&W[k * Nout + c * 4];
      const float a0 = sIn[(r * 4 + 0) * Kin + k];
      const float a1 = sIn[(r * 4 + 1) * Kin + k];
      const float a2 = sIn[(r * 4 + 2) * Kin + k];
      const float a3 = sIn[(r * 4 + 3) * Kin + k];
      acc[0][0] = fmaf(a0, wv.x, acc[0][0]);
      acc[0][1] = fmaf(a0, wv.y, acc[0][1]);
      acc[0][2] = fmaf(a0, wv.z, acc[0][2]);
      acc[0][3] = fmaf(a0, wv.w, acc[0][3]);
      acc[1][0] = fmaf(a1, wv.x, acc[1][0]);
      acc[1][1] = fmaf(a1, wv.y, acc[1][1]);
      acc[1][2] = fmaf(a1, wv.z, acc[1][2]);
      acc[1][3] = fmaf(a1, wv.w, acc[1][3]);
      acc[2][0] = fmaf(a2, wv.x, acc[2][0]);
      acc[2][1] = fmaf(a2, wv.y, acc[2][1]);
      acc[2][2] = fmaf(a2, wv.z, acc[2][2]);
      acc[2][3] = fmaf(a2, wv.w, acc[2][3]);
      acc[3][0] = fmaf(a3, wv.x, acc[3][0]);
      acc[3][1] = fmaf(a3, wv.y, acc[3][1]);
      acc[3][2] = fmaf(a3, wv.z, acc[3][2]);
      acc[3][3] = fmaf(a3, wv.w, acc[3][3]);
    }
    const float4 bv = *(const float4*)&bias[c * 4];
#pragma unroll
    for (int i = 0; i < 4; ++i) {
      const int row = row0 + r * 4 + i;
      if (row < G_N) {
        float4 v = make_float4(acc[i][0] + bv.x, acc[i][1] + bv.y,
                               acc[i][2] + bv.z, acc[i][3] + bv.w);
        if (RELU) {
          v.x = fmaxf(v.x, 0.f); v.y = fmaxf(v.y, 0.f);
          v.z = fmaxf(v.z, 0.f); v.w = fmaxf(v.w, 0.f);
        }
        *(float4*)&out[(size_t)row * Nout + c * 4] = v;
      }
    }
  }
}

// ---------------------------------------------------------------------------
extern "C" void kernel_launch(void* const* d_in, const int* in_sizes, int n_in,
                              void* d_out, int out_size, void* d_ws,
                              size_t ws_size, hipStream_t stream) {
  const float* feats = (const float*)d_in[0];
  const int* isrc = (const int*)d_in[1];
  const int* idst = (const int*)d_in[2];
  const int* osrc = (const int*)d_in[3];
  const int* odst = (const int*)d_in[4];
  const float* Wi0 = (const float*)d_in[5];
  const float* bi0 = (const float*)d_in[6];
  const float* Wi1 = (const float*)d_in[7];
  const float* bi1 = (const float*)d_in[8];
  const float* Wi2 = (const float*)d_in[9];
  const float* bi2 = (const float*)d_in[10];
  const float* Wo0 = (const float*)d_in[11];
  const float* bo0 = (const float*)d_in[12];
  const float* Wo1 = (const float*)d_in[13];
  const float* bo1 = (const float*)d_in[14];
  const float* Wo2 = (const float*)d_in[15];
  const float* bo2 = (const float*)d_in[16];
  float* out = (float*)d_out;

  float* ws = (float*)d_ws;
  float* feat = ws;                               // [G,128]
  float* h0   = ws + (size_t)G_N * HD;            // [G,128]
  float* agg  = ws + (size_t)2 * G_N * HD;        // [G,128]
  float* nrm  = ws + (size_t)3 * G_N * HD;        // [G]
  int* degi   = (int*)(ws + (size_t)3 * G_N * HD + G_N);
  int* start  = degi + G_N;
  int* cursor = start + G_N;
  int* esrc   = cursor + G_N;                     // [EO]
  short* wp0  = (short*)(esrc + EO_N);            // 8192 bf16
  short* wp1  = wp0 + 8 * 2 * 64 * 8;             // 16384 bf16
  short* wp2  = wp1 + 8 * 4 * 64 * 8;             // 16384 bf16

  // weight pre-pack (tiny; feeds inner kernel)
  pack_w_kernel<<<4, 256, 0, stream>>>(Wi0, FIN, wp0);
  pack_w_kernel<<<8, 256, 0, stream>>>(Wi1, HD, wp1);
  pack_w_kernel<<<8, 256, 0, stream>>>(Wi2, HD, wp2);

  // inner GCNs (MFMA) -> pooled graph features
  inner_gcn_kernel<<<G_N, 256, 0, stream>>>(feats, isrc, idst, wp0, bi0, wp1,
                                            bi1, wp2, bi2, feat);

  // CSR build for outer graph
  hipMemsetAsync(degi, 0, G_N * sizeof(int), stream);
  hist_kernel<<<(EO_N + 255) / 256, 256, 0, stream>>>(odst, degi);
  norm_kernel<<<(G_N + 255) / 256, 256, 0, stream>>>(degi, nrm);
  scan_kernel<<<1, 1024, 0, stream>>>(degi, start, cursor);
  fill_kernel<<<(EO_N + 255) / 256, 256, 0, stream>>>(osrc, odst, cursor, esrc);

  const int ggrid = (G_N + 7) / 8;
  const int mm_grid = (G_N + 31) / 32;

  gather_kernel<<<ggrid, 256, 0, stream>>>(feat, esrc, start, degi, nrm, agg);
  rowmm_kernel<HD, HD, true><<<mm_grid, 256, 0, stream>>>(agg, nrm, Wo0, bo0, h0);

  gather_kernel<<<ggrid, 256, 0, stream>>>(h0, esrc, start, degi, nrm, agg);
  rowmm_kernel<HD, HD, true><<<mm_grid, 256, 0, stream>>>(agg, nrm, Wo1, bo1, feat);

  gather_kernel<<<ggrid, 256, 0, stream>>>(feat, esrc, start, degi, nrm, agg);
  rowmm_kernel<HD, NCLS, false><<<mm_grid, 256, 0, stream>>>(agg, nrm, Wo2, bo2, out);
}

// Round 8
// 249.791 us; speedup vs baseline: 5.3560x; 1.0353x over previous
//
#include <hip/hip_runtime.h>
#include <math.h>

// Round 8: (a) outer fusion: gather+rowmm merged (agg buffer eliminated),
// norm folded into scan, 3 pack_w -> 1 launch (14 -> 9 dispatches);
// (b) inner: 24B/lane fragment slots (b16 scatter 8-way -> 4-way bank
// conflict) + wave-parallel deg-sum. Fragment math identical to round 7.

constexpr int G_N  = 10000;   // inner graphs / outer nodes
constexpr int NI_N = 32;      // nodes per inner graph
constexpr int EI_N = 128;     // edges per inner graph
constexpr int EO_N = 160000;  // outer edges
constexpr int FIN  = 64;      // inner input feature dim
constexpr int HD   = 128;     // hidden dim (= F_G)
constexpr int NCLS = 32;      // output classes

constexpr int LSTR = 12;      // shorts per lane slot (24B): bank (6*lane)%32
                              // -> 16 banks -> 4-way b16 conflicts (was 8-way
                              // at 16B), b64 stores stay 8B-aligned.

typedef short bf16x8 __attribute__((ext_vector_type(8)));
typedef float f32x4  __attribute__((ext_vector_type(4)));

#define MFMA16(a, b, c) __builtin_amdgcn_mfma_f32_16x16x32_bf16((a), (b), (c), 0, 0, 0)

__device__ __forceinline__ unsigned short f2bf(float x) {
  unsigned int u = __builtin_bit_cast(unsigned int, x);
  u += 0x7fffu + ((u >> 16) & 1u);
  return (unsigned short)(u >> 16);
}

// 16B fragment load from an 8B-aligned (not 16B) LDS address: two uint2 reads.
__device__ __forceinline__ bf16x8 ld_frag(const short* p) {
  union { bf16x8 v; uint2 u[2]; } x;
  x.u[0] = *(const uint2*)(p);
  x.u[1] = *(const uint2*)(p + 4);
  return x.v;
}

// ---------------------------------------------------------------------------
// Weight pre-pack (all three W in one launch; global layout unchanged, 16B/lane):
// Wpack[(ct*KB+kb)*64+lane][j] = W[32*kb + 8*(lane>>4) + j][16*ct + (lane&15)]
// ---------------------------------------------------------------------------
__global__ __launch_bounds__(256) void pack_all_w(
    const float* __restrict__ W0, const float* __restrict__ W1,
    const float* __restrict__ W2, short* __restrict__ o0,
    short* __restrict__ o1, short* __restrict__ o2) {
  const int b = blockIdx.x;
  const float* W; short* out; int K, idx;
  if (b < 4)       { W = W0; out = o0; K = 64;  idx = b * 256 + threadIdx.x; }
  else if (b < 12) { W = W1; out = o1; K = 128; idx = (b - 4) * 256 + threadIdx.x; }
  else             { W = W2; out = o2; K = 128; idx = (b - 12) * 256 + threadIdx.x; }
  const int KB = K >> 5;
  const int lane = idx & 63;
  const int ctkb = idx >> 6;
  const int kb = ctkb % KB;
  const int ct = ctkb / KB;
  const int col = 16 * ct + (lane & 15);
  const int k0 = 32 * kb + 8 * (lane >> 4);
#pragma unroll
  for (int j = 0; j < 8; ++j)
    out[idx * 8 + j] = (short)f2bf(W[(k0 + j) * HD + col]);
}

// ---------------------------------------------------------------------------
// One GCN layer in MFMA (identical math to round 7, LSTR-strided LDS images)
// ---------------------------------------------------------------------------
template <int NCT_IN, bool RELU, bool LAST>
__device__ __forceinline__ void gcn_layer(
    int w, int l, const short* __restrict__ sApackM, short* __restrict__ sHpack,
    short* __restrict__ sTpack, const short* __restrict__ Wpack,
    const float* __restrict__ bias, float* __restrict__ sPool) {
  constexpr int KB = NCT_IN / 2;
  const int rt = w >> 1;
  const int g = l >> 4, c15 = l & 15;
  const f32x4 z = {0.f, 0.f, 0.f, 0.f};

  // ---- step 1: T = M @ h ----
  const bf16x8 am = ld_frag(&sApackM[rt * (64 * LSTR) + l * LSTR]);
#pragma unroll
  for (int i = 0; i < NCT_IN / 2; ++i) {
    const int ct = (w & 1) * (NCT_IN / 2) + i;
    const bf16x8 bh = ld_frag(&sHpack[ct * (64 * LSTR) + l * LSTR]);
    f32x4 d = MFMA16(am, bh, z);
    const int kb = ct >> 1;
    const int hi = ((ct & 1) << 1) | (c15 >> 3);
    const int jj = l & 7;
#pragma unroll
    for (int r = 0; r < 4; ++r) {
      const int lanep = 4 * g + r + 16 * hi;
      sTpack[(rt * 4 + kb) * (64 * LSTR) + lanep * LSTR + jj] = (short)f2bf(d[r]);
    }
  }
  __syncthreads();

  // ---- step 2: H = T @ W (+bias, relu / pool) ----
  bf16x8 a[KB];
#pragma unroll
  for (int kb = 0; kb < KB; ++kb)
    a[kb] = ld_frag(&sTpack[(rt * 4 + kb) * (64 * LSTR) + l * LSTR]);
#pragma unroll
  for (int i = 0; i < 4; ++i) {
    const int ct2 = (w & 1) * 4 + i;
    f32x4 acc = z;
#pragma unroll
    for (int kb = 0; kb < KB; ++kb) {
      const bf16x8 bw = *(const bf16x8*)&Wpack[((ct2 * KB + kb) * 64 + l) * 8];
      acc = MFMA16(a[kb], bw, acc);
    }
    const int f = 16 * ct2 + c15;
    const float bv = bias[f];
    if (LAST) {
      const float s = (acc[0] + bv) + (acc[1] + bv) + (acc[2] + bv) + (acc[3] + bv);
      atomicAdd(&sPool[f], s);
    } else {
      unsigned short u[4];
#pragma unroll
      for (int r = 0; r < 4; ++r) {
        float v = acc[r] + bv;
        if (RELU) v = fmaxf(v, 0.f);
        u[r] = f2bf(v);
      }
      const int g2 = 2 * rt + (g >> 1);
      const int lanep = c15 + 16 * g2;
      const ushort4 pk = make_ushort4(u[0], u[1], u[2], u[3]);
      *(ushort4*)&sHpack[ct2 * (64 * LSTR) + lanep * LSTR + 4 * (g & 1)] = pk;
    }
  }
  __syncthreads();
}

__global__ __launch_bounds__(256) void inner_gcn_kernel(
    const float* __restrict__ feats, const int* __restrict__ src,
    const int* __restrict__ dst,
    const short* __restrict__ wp0, const float* __restrict__ bi0,
    const short* __restrict__ wp1, const float* __restrict__ bi1,
    const short* __restrict__ wp2, const float* __restrict__ bi2,
    float* __restrict__ feat_out) {
  __shared__ float sM[NI_N * 33];
  __shared__ float sNorm[NI_N];
  __shared__ __align__(16) short sApackM[2 * 64 * LSTR];
  __shared__ __align__(16) short sHpack[8 * 64 * LSTR];
  __shared__ __align__(16) short sTpack[8 * 64 * LSTR];
  __shared__ float sPool[HD];

  const int t = threadIdx.x;
  const int g = blockIdx.x;
  const int w = t >> 6, l = t & 63;

  // ---- build M = D^-1/2 A D^-1/2 ----
  for (int i = t; i < NI_N * 33; i += 256) sM[i] = 0.f;
  if (t < HD) sPool[t] = 0.f;
  __syncthreads();
  if (t < EI_N) {
    const int s = src[g * EI_N + t];
    const int d = dst[g * EI_N + t];
    atomicAdd(&sM[d * 33 + s], 1.0f);
  }
  __syncthreads();
  {
    // wave-parallel deg-sum: 8 threads per row + shfl reduce (was 32-serial)
    const int row = t >> 3, j = t & 7;
    float p = sM[row * 33 + j] + sM[row * 33 + 8 + j] +
              sM[row * 33 + 16 + j] + sM[row * 33 + 24 + j];
    p += __shfl_xor(p, 1);
    p += __shfl_xor(p, 2);
    p += __shfl_xor(p, 4);
    if (j == 0) sNorm[row] = (p > 0.f) ? (1.0f / sqrtf(p)) : 1.0f;
  }
  __syncthreads();
  for (int i = t; i < NI_N * NI_N; i += 256) {
    const int n = i >> 5, m = i & 31;
    sM[n * 33 + m] *= sNorm[n] * sNorm[m];
  }
  __syncthreads();

  // ---- pack M -> A-frag bf16 ----
  {
    const int rb = t >> 7;
    const int lane = (t >> 1) & 63;
    const int j0 = (t & 1) * 4;
    const int row = 16 * rb + (lane & 15);
    const int k0 = 8 * (lane >> 4) + j0;
#pragma unroll
    for (int jj = 0; jj < 4; ++jj)
      sApackM[rb * (64 * LSTR) + lane * LSTR + j0 + jj] =
          (short)f2bf(sM[row * 33 + k0 + jj]);
  }

  // ---- load h0 (32x64 fp32, coalesced float4) -> B-frag pack ----
  {
    const float4* f4 = (const float4*)(feats + (size_t)g * (NI_N * FIN));
    for (int idx = t; idx < NI_N * FIN / 4; idx += 256) {
      const int n = idx >> 4;
      const int f0 = (idx & 15) * 4;
      const float4 v = f4[idx];
      const int lanebase = 16 * (n >> 3);
      const int jj = n & 7;
      const int ct = f0 >> 4;
      const int c0 = f0 & 15;
      sHpack[ct * (64 * LSTR) + (c0 + 0 + lanebase) * LSTR + jj] = (short)f2bf(v.x);
      sHpack[ct * (64 * LSTR) + (c0 + 1 + lanebase) * LSTR + jj] = (short)f2bf(v.y);
      sHpack[ct * (64 * LSTR) + (c0 + 2 + lanebase) * LSTR + jj] = (short)f2bf(v.z);
      sHpack[ct * (64 * LSTR) + (c0 + 3 + lanebase) * LSTR + jj] = (short)f2bf(v.w);
    }
  }
  __syncthreads();

  // ---- 3 layers ----
  gcn_layer<4, true, false>(w, l, sApackM, sHpack, sTpack, wp0, bi0, sPool);
  gcn_layer<8, true, false>(w, l, sApackM, sHpack, sTpack, wp1, bi1, sPool);
  gcn_layer<8, false, true>(w, l, sApackM, sHpack, sTpack, wp2, bi2, sPool);

  // ---- mean over nodes ----
  if (t < HD) feat_out[(size_t)g * HD + t] = sPool[t] * (1.0f / NI_N);
}

// ---------------------------------------------------------------------------
// Outer GCN: CSR build + fused gather+matmul per layer (no agg buffer)
// ---------------------------------------------------------------------------
__global__ __launch_bounds__(256) void hist_kernel(const int* __restrict__ dst,
                                                   int* __restrict__ degi) {
  const int e = blockIdx.x * 256 + threadIdx.x;
  if (e < EO_N) atomicAdd(&degi[dst[e]], 1);
}

// single-block prefix scan over degi; also writes nrm (norm fold-in)
__global__ __launch_bounds__(1024) void scan_norm_kernel(
    const int* __restrict__ degi, int* __restrict__ start,
    int* __restrict__ cursor, float* __restrict__ nrm) {
  __shared__ int part[1024];
  const int t = threadIdx.x;
  const int base = t * 10;
  int loc[10];
  int s = 0;
#pragma unroll
  for (int k = 0; k < 10; ++k) {
    const int i = base + k;
    const int d = (i < G_N) ? degi[i] : 0;
    loc[k] = s;
    s += d;
  }
  part[t] = s;
  __syncthreads();
  for (int off = 1; off < 1024; off <<= 1) {
    const int v = (t >= off) ? part[t - off] : 0;
    __syncthreads();
    part[t] += v;
    __syncthreads();
  }
  const int excl = (t == 0) ? 0 : part[t - 1];
#pragma unroll
  for (int k = 0; k < 10; ++k) {
    const int i = base + k;
    if (i < G_N) {
      const int st = excl + loc[k];
      start[i] = st;
      cursor[i] = st;
      const int d = degi[i];
      nrm[i] = (d > 0) ? (1.0f / sqrtf((float)d)) : 1.0f;
    }
  }
}

__global__ __launch_bounds__(256) void fill_kernel(const int* __restrict__ src,
                                                   const int* __restrict__ dst,
                                                   int* __restrict__ cursor,
                                                   int* __restrict__ esrc) {
  const int e = blockIdx.x * 256 + threadIdx.x;
  if (e < EO_N) {
    const int pos = atomicAdd(&cursor[dst[e]], 1);
    esrc[pos] = src[e];
  }
}

// Fused: sIn[rr][:] = nrm[row] * sum_e h[src_e]*nrm[src_e]; out = relu?(sIn@W+b)
// 32 rows/block; phase 1: 8 threads/row gather 16 feats each; phase 2: rowmm.
template <int Nout, bool RELU>
__global__ __launch_bounds__(256) void gather_mm_kernel(
    const float* __restrict__ h, const int* __restrict__ esrc,
    const int* __restrict__ start, const int* __restrict__ degi,
    const float* __restrict__ nrm, const float* __restrict__ W,
    const float* __restrict__ bias, float* __restrict__ out) {
  __shared__ __align__(16) float sIn[32 * HD];
  const int t = threadIdx.x;
  const int row0 = blockIdx.x * 32;
  // ---- phase 1: gather into sIn ----
  {
    const int rr = t >> 3, sub = t & 7;  // 8 threads/row, 16 feats each
    const int row = row0 + rr;
    float4 a0 = {0,0,0,0}, a1 = {0,0,0,0}, a2 = {0,0,0,0}, a3 = {0,0,0,0};
    if (row < G_N) {
      const int s0 = start[row];
      const int cnt = degi[row];
      const float* hb = h + (size_t)sub * 16;
      for (int i = 0; i < cnt; ++i) {
        const int s = esrc[s0 + i];
        const float ns = nrm[s];
        const float* p = hb + (size_t)s * HD;
        const float4 v0 = *(const float4*)(p + 0);
        const float4 v1 = *(const float4*)(p + 4);
        const float4 v2 = *(const float4*)(p + 8);
        const float4 v3 = *(const float4*)(p + 12);
        a0.x = fmaf(v0.x, ns, a0.x); a0.y = fmaf(v0.y, ns, a0.y);
        a0.z = fmaf(v0.z, ns, a0.z); a0.w = fmaf(v0.w, ns, a0.w);
        a1.x = fmaf(v1.x, ns, a1.x); a1.y = fmaf(v1.y, ns, a1.y);
        a1.z = fmaf(v1.z, ns, a1.z); a1.w = fmaf(v1.w, ns, a1.w);
        a2.x = fmaf(v2.x, ns, a2.x); a2.y = fmaf(v2.y, ns, a2.y);
        a2.z = fmaf(v2.z, ns, a2.z); a2.w = fmaf(v2.w, ns, a2.w);
        a3.x = fmaf(v3.x, ns, a3.x); a3.y = fmaf(v3.y, ns, a3.y);
        a3.z = fmaf(v3.z, ns, a3.z); a3.w = fmaf(v3.w, ns, a3.w);
      }
      const float nr = nrm[row];
      a0.x *= nr; a0.y *= nr; a0.z *= nr; a0.w *= nr;
      a1.x *= nr; a1.y *= nr; a1.z *= nr; a1.w *= nr;
      a2.x *= nr; a2.y *= nr; a2.z *= nr; a2.w *= nr;
      a3.x *= nr; a3.y *= nr; a3.z *= nr; a3.w *= nr;
    }
    float* q = &sIn[rr * HD + sub * 16];
    *(float4*)(q + 0) = a0;
    *(float4*)(q + 4) = a1;
    *(float4*)(q + 8) = a2;
    *(float4*)(q + 12) = a3;
  }
  __syncthreads();
  // ---- phase 2: mm ----
  constexpr int NC4 = Nout / 4;
  constexpr int TILES = 8 * NC4;
  if (t < TILES) {
    const int r = t / NC4, c = t % NC4;
    float acc[4][4] = {};
#pragma unroll 8
    for (int k = 0; k < HD; ++k) {
      const float4 wv = *(const float4*)&W[k * Nout + c * 4];
      const float a0 = sIn[(r * 4 + 0) * HD + k];
      const float a1 = sIn[(r * 4 + 1) * HD + k];
      const float a2 = sIn[(r * 4 + 2) * HD + k];
      const float a3 = sIn[(r * 4 + 3) * HD + k];
      acc[0][0] = fmaf(a0, wv.x, acc[0][0]);
      acc[0][1] = fmaf(a0, wv.y, acc[0][1]);
      acc[0][2] = fmaf(a0, wv.z, acc[0][2]);
      acc[0][3] = fmaf(a0, wv.w, acc[0][3]);
      acc[1][0] = fmaf(a1, wv.x, acc[1][0]);
      acc[1][1] = fmaf(a1, wv.y, acc[1][1]);
      acc[1][2] = fmaf(a1, wv.z, acc[1][2]);
      acc[1][3] = fmaf(a1, wv.w, acc[1][3]);
      acc[2][0] = fmaf(a2, wv.x, acc[2][0]);
      acc[2][1] = fmaf(a2, wv.y, acc[2][1]);
      acc[2][2] = fmaf(a2, wv.z, acc[2][2]);
      acc[2][3] = fmaf(a2, wv.w, acc[2][3]);
      acc[3][0] = fmaf(a3, wv.x, acc[3][0]);
      acc[3][1] = fmaf(a3, wv.y, acc[3][1]);
      acc[3][2] = fmaf(a3, wv.z, acc[3][2]);
      acc[3][3] = fmaf(a3, wv.w, acc[3][3]);
    }
    const float4 bv = *(const float4*)&bias[c * 4];
#pragma unroll
    for (int i = 0; i < 4; ++i) {
      const int row = row0 + r * 4 + i;
      if (row < G_N) {
        float4 v = make_float4(acc[i][0] + bv.x, acc[i][1] + bv.y,
                               acc[i][2] + bv.z, acc[i][3] + bv.w);
        if (RELU) {
          v.x = fmaxf(v.x, 0.f); v.y = fmaxf(v.y, 0.f);
          v.z = fmaxf(v.z, 0.f); v.w = fmaxf(v.w, 0.f);
        }
        *(float4*)&out[(size_t)row * Nout + c * 4] = v;
      }
    }
  }
}

// ---------------------------------------------------------------------------
extern "C" void kernel_launch(void* const* d_in, const int* in_sizes, int n_in,
                              void* d_out, int out_size, void* d_ws,
                              size_t ws_size, hipStream_t stream) {
  const float* feats = (const float*)d_in[0];
  const int* isrc = (const int*)d_in[1];
  const int* idst = (const int*)d_in[2];
  const int* osrc = (const int*)d_in[3];
  const int* odst = (const int*)d_in[4];
  const float* Wi0 = (const float*)d_in[5];
  const float* bi0 = (const float*)d_in[6];
  const float* Wi1 = (const float*)d_in[7];
  const float* bi1 = (const float*)d_in[8];
  const float* Wi2 = (const float*)d_in[9];
  const float* bi2 = (const float*)d_in[10];
  const float* Wo0 = (const float*)d_in[11];
  const float* bo0 = (const float*)d_in[12];
  const float* Wo1 = (const float*)d_in[13];
  const float* bo1 = (const float*)d_in[14];
  const float* Wo2 = (const float*)d_in[15];
  const float* bo2 = (const float*)d_in[16];
  float* out = (float*)d_out;

  float* ws = (float*)d_ws;
  float* feat = ws;                               // [G,128]
  float* h0   = ws + (size_t)G_N * HD;            // [G,128]
  float* nrm  = ws + (size_t)3 * G_N * HD;        // [G]
  int* degi   = (int*)(ws + (size_t)3 * G_N * HD + G_N);
  int* start  = degi + G_N;
  int* cursor = start + G_N;
  int* esrc   = cursor + G_N;                     // [EO]
  short* wp0  = (short*)(esrc + EO_N);            // 8192 bf16
  short* wp1  = wp0 + 8 * 2 * 64 * 8;             // 16384 bf16
  short* wp2  = wp1 + 8 * 4 * 64 * 8;             // 16384 bf16

  // weight pre-pack (one launch)
  pack_all_w<<<20, 256, 0, stream>>>(Wi0, Wi1, Wi2, wp0, wp1, wp2);

  // inner GCNs (MFMA) -> pooled graph features
  inner_gcn_kernel<<<G_N, 256, 0, stream>>>(feats, isrc, idst, wp0, bi0, wp1,
                                            bi1, wp2, bi2, feat);

  // CSR build for outer graph
  hipMemsetAsync(degi, 0, G_N * sizeof(int), stream);
  hist_kernel<<<(EO_N + 255) / 256, 256, 0, stream>>>(odst, degi);
  scan_norm_kernel<<<1, 1024, 0, stream>>>(degi, start, cursor, nrm);
  fill_kernel<<<(EO_N + 255) / 256, 256, 0, stream>>>(osrc, odst, cursor, esrc);

  const int gm_grid = (G_N + 31) / 32;
  gather_mm_kernel<HD, true><<<gm_grid, 256, 0, stream>>>(
      feat, esrc, start, degi, nrm, Wo0, bo0, h0);
  gather_mm_kernel<HD, true><<<gm_grid, 256, 0, stream>>>(
      h0, esrc, start, degi, nrm, Wo1, bo1, feat);
  gather_mm_kernel<NCLS, false><<<gm_grid, 256, 0, stream>>>(
      feat, esrc, start, degi, nrm, Wo2, bo2, out);
}

// Round 9
// 179.677 us; speedup vs baseline: 7.4460x; 1.3902x over previous
//
#include <hip/hip_runtime.h>
#include <math.h>

// Round 9: inner rewritten graph-per-wave (64-thr blocks, ZERO __syncthreads:
// all LDS deps intra-wave; 8 independent graphs/CU overlap latency). feats
// prefetch, norm folded into M-pack, W loads shared across row-tiles, pool in
// regs via shfl. Outer: gather_mm 16 rows/block (625 blocks) + 2-way edge split.

constexpr int G_N  = 10000;
constexpr int NI_N = 32;
constexpr int EI_N = 128;
constexpr int EO_N = 160000;
constexpr int FIN  = 64;
constexpr int HD   = 128;
constexpr int NCLS = 32;

typedef short bf16x8 __attribute__((ext_vector_type(8)));
typedef float f32x4  __attribute__((ext_vector_type(4)));

#define MFMA16(a, b, c) __builtin_amdgcn_mfma_f32_16x16x32_bf16((a), (b), (c), 0, 0, 0)

__device__ __forceinline__ unsigned short f2bf(float x) {
  unsigned int u = __builtin_bit_cast(unsigned int, x);
  u += 0x7fffu + ((u >> 16) & 1u);
  return (unsigned short)(u >> 16);
}

// ---------------------------------------------------------------------------
// Weight pre-pack: W[K][128] fp32 -> B-frag bf16 (one launch, 3 weights)
// Wpack[(ct*KB+kb)*64+lane][j] = W[32*kb + 8*(lane>>4) + j][16*ct + (lane&15)]
// ---------------------------------------------------------------------------
__global__ __launch_bounds__(256) void pack_all_w(
    const float* __restrict__ W0, const float* __restrict__ W1,
    const float* __restrict__ W2, short* __restrict__ o0,
    short* __restrict__ o1, short* __restrict__ o2) {
  const int b = blockIdx.x;
  const float* W; short* out; int K, idx;
  if (b < 4)       { W = W0; out = o0; K = 64;  idx = b * 256 + threadIdx.x; }
  else if (b < 12) { W = W1; out = o1; K = 128; idx = (b - 4) * 256 + threadIdx.x; }
  else             { W = W2; out = o2; K = 128; idx = (b - 12) * 256 + threadIdx.x; }
  const int KB = K >> 5;
  const int lane = idx & 63;
  const int ctkb = idx >> 6;
  const int kb = ctkb % KB;
  const int ct = ctkb / KB;
  const int col = 16 * ct + (lane & 15);
  const int k0 = 32 * kb + 8 * (lane >> 4);
#pragma unroll
  for (int j = 0; j < 8; ++j)
    out[idx * 8 + j] = (short)f2bf(W[(k0 + j) * HD + col]);
}

// ---------------------------------------------------------------------------
// One GCN layer, single wave owns the whole graph (no barriers).
//   step1: T = M @ h  -> A-frag repack into sT
//   step2: H = T @ W  (+bias, relu) -> B-frag repack into sH; LAST: reg pool
// ---------------------------------------------------------------------------
template <int NCT, bool RELU, bool LAST>
__device__ __forceinline__ void gcn_layer_w(
    int l, const short* __restrict__ sMp, short* __restrict__ sH,
    short* __restrict__ sT, const short* __restrict__ Wp,
    const float* __restrict__ bias, float* __restrict__ outp) {
  constexpr int KB = NCT / 2;
  const int lg = l >> 4, c15 = l & 15, jj = l & 7;
  const f32x4 z = {0.f, 0.f, 0.f, 0.f};

  // ---- step1: T = M @ h ----
#pragma unroll
  for (int rt = 0; rt < 2; ++rt) {
    const bf16x8 am = *(const bf16x8*)&sMp[(rt * 64 + l) * 8];
#pragma unroll
    for (int ct = 0; ct < NCT; ++ct) {
      const bf16x8 bh = *(const bf16x8*)&sH[(ct * 64 + l) * 8];
      f32x4 d = MFMA16(am, bh, z);
      const int kb = ct >> 1;
      const int hi = ((ct & 1) << 1) | (c15 >> 3);
      const int base = ((rt * 4 + kb) * 64 + 16 * hi + 4 * lg) * 8 + jj;
#pragma unroll
      for (int r = 0; r < 4; ++r) sT[base + r * 8] = (short)f2bf(d[r]);
    }
  }

  // ---- step2: H = T @ W (W loads shared across both row-tiles) ----
  bf16x8 a0[KB], a1[KB];
#pragma unroll
  for (int kb = 0; kb < KB; ++kb) {
    a0[kb] = *(const bf16x8*)&sT[((0 + kb) * 64 + l) * 8];
    a1[kb] = *(const bf16x8*)&sT[((4 + kb) * 64 + l) * 8];
  }
  float pool[8];
#pragma unroll
  for (int ct2 = 0; ct2 < 8; ++ct2) {
    f32x4 acc0 = z, acc1 = z;
#pragma unroll
    for (int kb = 0; kb < KB; ++kb) {
      const bf16x8 bw = *(const bf16x8*)&Wp[((ct2 * KB + kb) * 64 + l) * 8];
      acc0 = MFMA16(a0[kb], bw, acc0);
      acc1 = MFMA16(a1[kb], bw, acc1);
    }
    const float bv = bias[16 * ct2 + c15];
    if (LAST) {
      pool[ct2] = (acc0[0] + acc0[1] + acc0[2] + acc0[3]) +
                  (acc1[0] + acc1[1] + acc1[2] + acc1[3]) + 8.f * bv;
    } else {
      {  // rt = 0: rows 4*lg..4*lg+3
        float v0 = acc0[0] + bv, v1 = acc0[1] + bv, v2 = acc0[2] + bv, v3 = acc0[3] + bv;
        if (RELU) { v0 = fmaxf(v0, 0.f); v1 = fmaxf(v1, 0.f);
                    v2 = fmaxf(v2, 0.f); v3 = fmaxf(v3, 0.f); }
        const ushort4 pk = make_ushort4(f2bf(v0), f2bf(v1), f2bf(v2), f2bf(v3));
        const int g2 = (lg >> 1);
        *(ushort4*)&sH[(ct2 * 64 + c15 + 16 * g2) * 8 + 4 * (lg & 1)] = pk;
      }
      {  // rt = 1: rows 16+4*lg..
        float v0 = acc1[0] + bv, v1 = acc1[1] + bv, v2 = acc1[2] + bv, v3 = acc1[3] + bv;
        if (RELU) { v0 = fmaxf(v0, 0.f); v1 = fmaxf(v1, 0.f);
                    v2 = fmaxf(v2, 0.f); v3 = fmaxf(v3, 0.f); }
        const ushort4 pk = make_ushort4(f2bf(v0), f2bf(v1), f2bf(v2), f2bf(v3));
        const int g2 = 2 + (lg >> 1);
        *(ushort4*)&sH[(ct2 * 64 + c15 + 16 * g2) * 8 + 4 * (lg & 1)] = pk;
      }
    }
  }
  if (LAST) {
    // lane (lg,c15) holds col sums over its 8 rows; reduce over lg, write mean
#pragma unroll
    for (int ct2 = 0; ct2 < 8; ++ct2) {
      float p = pool[ct2];
      p += __shfl_xor(p, 16);
      p += __shfl_xor(p, 32);
      if (l < 16) outp[16 * ct2 + c15] = p * (1.0f / NI_N);
    }
  }
}

__global__ __launch_bounds__(64) void inner_gcn_kernel(
    const float* __restrict__ feats, const int* __restrict__ src,
    const int* __restrict__ dst,
    const short* __restrict__ wp0, const float* __restrict__ bi0,
    const short* __restrict__ wp1, const float* __restrict__ bi1,
    const short* __restrict__ wp2, const float* __restrict__ bi2,
    float* __restrict__ feat_out) {
  __shared__ __align__(16) short sH[8 * 64 * 8];   // 8KB  B-frag h
  __shared__ __align__(16) short sT[8 * 64 * 8];   // 8KB  A-frag T / f32 M build
  __shared__ __align__(16) short sMp[2 * 64 * 8];  // 2KB  A-frag norm'd M
  __shared__ float sNorm[NI_N];

  const int l = threadIdx.x;       // single wave
  const int gid = blockIdx.x;
  const int lg = l >> 4, c15 = l & 15;
  float* sMf = (float*)sT;         // 32 x 36 f32 build area (4608B <= 8KB)

  // ---- prefetch h0 (issue HBM loads first; latency hides under M build) ----
  const float4* f4 = (const float4*)(feats + (size_t)gid * (NI_N * FIN));
  float4 hv[8];
#pragma unroll
  for (int it = 0; it < 8; ++it) hv[it] = f4[it * 64 + l];

  // ---- edges (2 per lane) ----
  const int2 es = ((const int2*)(src + gid * EI_N))[l];
  const int2 ed = ((const int2*)(dst + gid * EI_N))[l];

  // ---- build M: zero, edge atomics (wave-private LDS) ----
#pragma unroll
  for (int i = 0; i < 18; ++i) sMf[i * 64 + l] = 0.f;
  atomicAdd(&sMf[ed.x * 36 + es.x], 1.0f);
  atomicAdd(&sMf[ed.y * 36 + es.y], 1.0f);

  // ---- deg + norm: 2 lanes/row, float4 row reads, shfl combine ----
  {
    const int row = l & 31;
    const float* pr = &sMf[row * 36 + (l >> 5) * 16];
    const float4 q0 = *(const float4*)(pr + 0);
    const float4 q1 = *(const float4*)(pr + 4);
    const float4 q2 = *(const float4*)(pr + 8);
    const float4 q3 = *(const float4*)(pr + 12);
    float p = (q0.x + q0.y + q0.z + q0.w) + (q1.x + q1.y + q1.z + q1.w) +
              (q2.x + q2.y + q2.z + q2.w) + (q3.x + q3.y + q3.z + q3.w);
    p += __shfl_xor(p, 32);
    if (l < 32) sNorm[l] = (p > 0.f) ? (1.0f / sqrtf(p)) : 1.0f;
  }

  // ---- pack M -> A-frag with norm scaling fused ----
  {
    const int k0 = 8 * lg;
    const float4 n0 = *(const float4*)&sNorm[k0];
    const float4 n1 = *(const float4*)&sNorm[k0 + 4];
#pragma unroll
    for (int rb = 0; rb < 2; ++rb) {
      const int row = 16 * rb + c15;
      const float nr = sNorm[row];
      const float4 a = *(const float4*)&sMf[row * 36 + k0];
      const float4 b = *(const float4*)&sMf[row * 36 + k0 + 4];
      bf16x8 o;
      o[0] = (short)f2bf(a.x * nr * n0.x); o[1] = (short)f2bf(a.y * nr * n0.y);
      o[2] = (short)f2bf(a.z * nr * n0.z); o[3] = (short)f2bf(a.w * nr * n0.w);
      o[4] = (short)f2bf(b.x * nr * n1.x); o[5] = (short)f2bf(b.y * nr * n1.y);
      o[6] = (short)f2bf(b.z * nr * n1.z); o[7] = (short)f2bf(b.w * nr * n1.w);
      *(bf16x8*)&sMp[(rb * 64 + l) * 8] = o;
    }
  }

  // ---- pack h0 -> B-frag (data already in regs) ----
#pragma unroll
  for (int it = 0; it < 8; ++it) {
    const int n = it * 4 + lg;        // node
    const int ct = c15 >> 2;          // feat tile
    const int c0 = (c15 & 3) * 4;
    const int lanebase = 16 * (n >> 3);
    const int jj = n & 7;
    const float4 v = hv[it];
    sH[(ct * 64 + c0 + 0 + lanebase) * 8 + jj] = (short)f2bf(v.x);
    sH[(ct * 64 + c0 + 1 + lanebase) * 8 + jj] = (short)f2bf(v.y);
    sH[(ct * 64 + c0 + 2 + lanebase) * 8 + jj] = (short)f2bf(v.z);
    sH[(ct * 64 + c0 + 3 + lanebase) * 8 + jj] = (short)f2bf(v.w);
  }

  // ---- 3 layers (sT overwrite of sMf is after all sMf reads: program order) --
  gcn_layer_w<4, true, false>(l, sMp, sH, sT, wp0, bi0, nullptr);
  gcn_layer_w<8, true, false>(l, sMp, sH, sT, wp1, bi1, nullptr);
  gcn_layer_w<8, false, true>(l, sMp, sH, sT, wp2, bi2,
                              feat_out + (size_t)gid * HD);
}

// ---------------------------------------------------------------------------
// Outer GCN: CSR build + fused gather+matmul (16 rows/block, 2-way edge split)
// ---------------------------------------------------------------------------
__global__ __launch_bounds__(256) void hist_kernel(const int* __restrict__ dst,
                                                   int* __restrict__ degi) {
  const int e = blockIdx.x * 256 + threadIdx.x;
  if (e < EO_N) atomicAdd(&degi[dst[e]], 1);
}

__global__ __launch_bounds__(1024) void scan_norm_kernel(
    const int* __restrict__ degi, int* __restrict__ start,
    int* __restrict__ cursor, float* __restrict__ nrm) {
  __shared__ int part[1024];
  const int t = threadIdx.x;
  const int base = t * 10;
  int loc[10];
  int s = 0;
#pragma unroll
  for (int k = 0; k < 10; ++k) {
    const int i = base + k;
    const int d = (i < G_N) ? degi[i] : 0;
    loc[k] = s;
    s += d;
  }
  part[t] = s;
  __syncthreads();
  for (int off = 1; off < 1024; off <<= 1) {
    const int v = (t >= off) ? part[t - off] : 0;
    __syncthreads();
    part[t] += v;
    __syncthreads();
  }
  const int excl = (t == 0) ? 0 : part[t - 1];
#pragma unroll
  for (int k = 0; k < 10; ++k) {
    const int i = base + k;
    if (i < G_N) {
      const int st = excl + loc[k];
      start[i] = st;
      cursor[i] = st;
      const int d = degi[i];
      nrm[i] = (d > 0) ? (1.0f / sqrtf((float)d)) : 1.0f;
    }
  }
}

__global__ __launch_bounds__(256) void fill_kernel(const int* __restrict__ src,
                                                   const int* __restrict__ dst,
                                                   int* __restrict__ cursor,
                                                   int* __restrict__ esrc) {
  const int e = blockIdx.x * 256 + threadIdx.x;
  if (e < EO_N) {
    const int pos = atomicAdd(&cursor[dst[e]], 1);
    esrc[pos] = src[e];
  }
}

// 16 rows/block (625*16 == G_N exactly). Phase1: 16 thr/row = 2 edge-halves x
// 8 feat-groups; deterministic two-step combine. Phase2: rowmm from LDS.
template <int Nout, bool RELU>
__global__ __launch_bounds__(256) void gather_mm_kernel(
    const float* __restrict__ h, const int* __restrict__ esrc,
    const int* __restrict__ start, const int* __restrict__ degi,
    const float* __restrict__ nrm, const float* __restrict__ W,
    const float* __restrict__ bias, float* __restrict__ out) {
  __shared__ __align__(16) float sIn[16 * HD];
  const int t = threadIdx.x;
  const int row0 = blockIdx.x * 16;
  const int rr = t >> 4, sub = t & 15;
  const int ehalf = sub >> 3, fq = sub & 7;
  const int row = row0 + rr;
  float4 a0 = {0,0,0,0}, a1 = {0,0,0,0}, a2 = {0,0,0,0}, a3 = {0,0,0,0};
  {
    const int s0 = start[row];
    const int cnt = degi[row];
    const float* hb = h + (size_t)fq * 16;
    for (int i = ehalf; i < cnt; i += 2) {
      const int s = esrc[s0 + i];
      const float ns = nrm[s];
      const float* p = hb + (size_t)s * HD;
      const float4 v0 = *(const float4*)(p + 0);
      const float4 v1 = *(const float4*)(p + 4);
      const float4 v2 = *(const float4*)(p + 8);
      const float4 v3 = *(const float4*)(p + 12);
      a0.x = fmaf(v0.x, ns, a0.x); a0.y = fmaf(v0.y, ns, a0.y);
      a0.z = fmaf(v0.z, ns, a0.z); a0.w = fmaf(v0.w, ns, a0.w);
      a1.x = fmaf(v1.x, ns, a1.x); a1.y = fmaf(v1.y, ns, a1.y);
      a1.z = fmaf(v1.z, ns, a1.z); a1.w = fmaf(v1.w, ns, a1.w);
      a2.x = fmaf(v2.x, ns, a2.x); a2.y = fmaf(v2.y, ns, a2.y);
      a2.z = fmaf(v2.z, ns, a2.z); a2.w = fmaf(v2.w, ns, a2.w);
      a3.x = fmaf(v3.x, ns, a3.x); a3.y = fmaf(v3.y, ns, a3.y);
      a3.z = fmaf(v3.z, ns, a3.z); a3.w = fmaf(v3.w, ns, a3.w);
    }
  }
  float* q = &sIn[rr * HD + fq * 16];
  if (ehalf == 0) {
    *(float4*)(q + 0) = a0; *(float4*)(q + 4) = a1;
    *(float4*)(q + 8) = a2; *(float4*)(q + 12) = a3;
  }
  __syncthreads();
  if (ehalf == 1) {
    const float nr = nrm[row];
    float4 b0 = *(const float4*)(q + 0), b1 = *(const float4*)(q + 4);
    float4 b2 = *(const float4*)(q + 8), b3 = *(const float4*)(q + 12);
    b0.x = (b0.x + a0.x) * nr; b0.y = (b0.y + a0.y) * nr;
    b0.z = (b0.z + a0.z) * nr; b0.w = (b0.w + a0.w) * nr;
    b1.x = (b1.x + a1.x) * nr; b1.y = (b1.y + a1.y) * nr;
    b1.z = (b1.z + a1.z) * nr; b1.w = (b1.w + a1.w) * nr;
    b2.x = (b2.x + a2.x) * nr; b2.y = (b2.y + a2.y) * nr;
    b2.z = (b2.z + a2.z) * nr; b2.w = (b2.w + a2.w) * nr;
    b3.x = (b3.x + a3.x) * nr; b3.y = (b3.y + a3.y) * nr;
    b3.z = (b3.z + a3.z) * nr; b3.w = (b3.w + a3.w) * nr;
    *(float4*)(q + 0) = b0; *(float4*)(q + 4) = b1;
    *(float4*)(q + 8) = b2; *(float4*)(q + 12) = b3;
  }
  __syncthreads();
  // ---- mm phase: 4 row-groups x NC4 col-groups ----
  constexpr int NC4 = Nout / 4;
  constexpr int TILES = 4 * NC4;
  if (t < TILES) {
    const int r = t / NC4, c = t % NC4;
    float acc[4][4] = {};
#pragma unroll 8
    for (int k = 0; k < HD; ++k) {
      const float4 wv = *(const float4*)&W[k * Nout + c * 4];
      const float a0s = sIn[(r * 4 + 0) * HD + k];
      const float a1s = sIn[(r * 4 + 1) * HD + k];
      const float a2s = sIn[(r * 4 + 2) * HD + k];
      const float a3s = sIn[(r * 4 + 3) * HD + k];
      acc[0][0] = fmaf(a0s, wv.x, acc[0][0]);
      acc[0][1] = fmaf(a0s, wv.y, acc[0][1]);
      acc[0][2] = fmaf(a0s, wv.z, acc[0][2]);
      acc[0][3] = fmaf(a0s, wv.w, acc[0][3]);
      acc[1][0] = fmaf(a1s, wv.x, acc[1][0]);
      acc[1][1] = fmaf(a1s, wv.y, acc[1][1]);
      acc[1][2] = fmaf(a1s, wv.z, acc[1][2]);
      acc[1][3] = fmaf(a1s, wv.w, acc[1][3]);
      acc[2][0] = fmaf(a2s, wv.x, acc[2][0]);
      acc[2][1] = fmaf(a2s, wv.y, acc[2][1]);
      acc[2][2] = fmaf(a2s, wv.z, acc[2][2]);
      acc[2][3] = fmaf(a2s, wv.w, acc[2][3]);
      acc[3][0] = fmaf(a3s, wv.x, acc[3][0]);
      acc[3][1] = fmaf(a3s, wv.y, acc[3][1]);
      acc[3][2] = fmaf(a3s, wv.z, acc[3][2]);
      acc[3][3] = fmaf(a3s, wv.w, acc[3][3]);
    }
    const float4 bv = *(const float4*)&bias[c * 4];
#pragma unroll
    for (int i = 0; i < 4; ++i) {
      float4 v = make_float4(acc[i][0] + bv.x, acc[i][1] + bv.y,
                             acc[i][2] + bv.z, acc[i][3] + bv.w);
      if (RELU) {
        v.x = fmaxf(v.x, 0.f); v.y = fmaxf(v.y, 0.f);
        v.z = fmaxf(v.z, 0.f); v.w = fmaxf(v.w, 0.f);
      }
      *(float4*)&out[(size_t)(row0 + r * 4 + i) * Nout + c * 4] = v;
    }
  }
}

// ---------------------------------------------------------------------------
extern "C" void kernel_launch(void* const* d_in, const int* in_sizes, int n_in,
                              void* d_out, int out_size, void* d_ws,
                              size_t ws_size, hipStream_t stream) {
  const float* feats = (const float*)d_in[0];
  const int* isrc = (const int*)d_in[1];
  const int* idst = (const int*)d_in[2];
  const int* osrc = (const int*)d_in[3];
  const int* odst = (const int*)d_in[4];
  const float* Wi0 = (const float*)d_in[5];
  const float* bi0 = (const float*)d_in[6];
  const float* Wi1 = (const float*)d_in[7];
  const float* bi1 = (const float*)d_in[8];
  const float* Wi2 = (const float*)d_in[9];
  const float* bi2 = (const float*)d_in[10];
  const float* Wo0 = (const float*)d_in[11];
  const float* bo0 = (const float*)d_in[12];
  const float* Wo1 = (const float*)d_in[13];
  const float* bo1 = (const float*)d_in[14];
  const float* Wo2 = (const float*)d_in[15];
  const float* bo2 = (const float*)d_in[16];
  float* out = (float*)d_out;

  float* ws = (float*)d_ws;
  float* feat = ws;                               // [G,128]
  float* h0   = ws + (size_t)G_N * HD;            // [G,128]
  float* nrm  = ws + (size_t)3 * G_N * HD;        // [G]
  int* degi   = (int*)(ws + (size_t)3 * G_N * HD + G_N);
  int* start  = degi + G_N;
  int* cursor = start + G_N;
  int* esrc   = cursor + G_N;                     // [EO]
  short* wp0  = (short*)(esrc + EO_N);            // 8192 bf16
  short* wp1  = wp0 + 8 * 2 * 64 * 8;             // 16384 bf16
  short* wp2  = wp1 + 8 * 4 * 64 * 8;             // 16384 bf16

  pack_all_w<<<20, 256, 0, stream>>>(Wi0, Wi1, Wi2, wp0, wp1, wp2);

  // inner GCNs: one wave per graph
  inner_gcn_kernel<<<G_N, 64, 0, stream>>>(feats, isrc, idst, wp0, bi0, wp1,
                                           bi1, wp2, bi2, feat);

  // CSR build for outer graph
  hipMemsetAsync(degi, 0, G_N * sizeof(int), stream);
  hist_kernel<<<(EO_N + 255) / 256, 256, 0, stream>>>(odst, degi);
  scan_norm_kernel<<<1, 1024, 0, stream>>>(degi, start, cursor, nrm);
  fill_kernel<<<(EO_N + 255) / 256, 256, 0, stream>>>(osrc, odst, cursor, esrc);

  const int gm_grid = G_N / 16;   // 625, exact
  gather_mm_kernel<HD, true><<<gm_grid, 256, 0, stream>>>(
      feat, esrc, start, degi, nrm, Wo0, bo0, h0);
  gather_mm_kernel<HD, true><<<gm_grid, 256, 0, stream>>>(
      h0, esrc, start, degi, nrm, Wo1, bo1, feat);
  gather_mm_kernel<NCLS, false><<<gm_grid, 256, 0, stream>>>(
      feat, esrc, start, degi, nrm, Wo2, bo2, out);
}